// Round 15
// baseline (784.445 us; speedup 1.0000x reference)
//
#include <hip/hip_runtime.h>
#include <math.h>

#define TT 4096
#define BB 2
#define MMDIM 256
#define RTOT 8192
#define NSLICE 39

typedef __attribute__((ext_vector_type(8))) short short8_t;
typedef __attribute__((ext_vector_type(4))) float f32x4;

// ---------------------------------------------------------------------------
// f32 -> bf16 hi/lo split helpers (RNE both stages).
// ---------------------------------------------------------------------------
__device__ __forceinline__ unsigned short f2bf(float x)
{
    unsigned u = __float_as_uint(x);
    u += 0x7fffu + ((u >> 16) & 1u);
    return (unsigned short)(u >> 16);
}

__device__ __forceinline__ void split4(const float* src, unsigned short* hi,
                                       unsigned short* lo, int i)
{
    float4 x = ((const float4*)src)[i];
    ushort4 h, l;
    h.x = f2bf(x.x); l.x = f2bf(x.x - __uint_as_float((unsigned)h.x << 16));
    h.y = f2bf(x.y); l.y = f2bf(x.y - __uint_as_float((unsigned)h.y << 16));
    h.z = f2bf(x.z); l.z = f2bf(x.z - __uint_as_float((unsigned)h.z << 16));
    h.w = f2bf(x.w); l.w = f2bf(x.w - __uint_as_float((unsigned)h.w << 16));
    ((ushort4*)hi)[i] = h;
    ((ushort4*)lo)[i] = l;
}

// ---------------------------------------------------------------------------
// L1: fused q+k f32 GEMM (R11 proven shape, bit-identical q,k) + all weight
// splits. Block ranges: [0,512) qk; [512,768) Ws1; [768,1024) Wv;
// [1024,1088) Wsr; [1088,1344) Wo.
// ---------------------------------------------------------------------------
__global__ __launch_bounds__(256) void gemm_qk_split(
    const float* __restrict__ mu, const float* __restrict__ Wq,
    const float* __restrict__ bq, const float* __restrict__ Wk,
    const float* __restrict__ bk, float* __restrict__ q_, float* __restrict__ k_,
    unsigned short* __restrict__ qkh, unsigned short* __restrict__ qkl,
    const float* __restrict__ Ws1, const float* __restrict__ Wv,
    const float* __restrict__ Wsr, const float* __restrict__ Wo,
    unsigned short* __restrict__ w1h, unsigned short* __restrict__ w1l,
    unsigned short* __restrict__ wvh, unsigned short* __restrict__ wvl,
    unsigned short* __restrict__ wsrh, unsigned short* __restrict__ wsrl,
    unsigned short* __restrict__ woh, unsigned short* __restrict__ wol)
{
    __shared__ float As[2][8][68];
    __shared__ float Ws[2][8][132];
    const int bid = blockIdx.x;
    const int tid = threadIdx.x;

    if (bid >= 512) {
        const int sid = bid - 512;
        if (sid < 256) {
            int r = sid;
            for (int c = tid; c < 2112; c += 256) {
                float v = (c < 2055) ? Ws1[(size_t)r * 2055 + c] : 0.f;
                unsigned short h = f2bf(v);
                w1h[(size_t)r * 2112 + c] = h;
                w1l[(size_t)r * 2112 + c] = f2bf(v - __uint_as_float((unsigned)h << 16));
            }
        } else if (sid < 512) {
            split4(Wv, wvh, wvl, (sid - 256) * 256 + tid);
        } else if (sid < 576) {
            split4(Wsr, wsrh, wsrl, (sid - 512) * 256 + tid);
        } else {
            split4(Wo, woh, wol, (sid - 576) * 256 + tid);
        }
        return;
    }

    const int bx = bid >> 2;
    const int by = bid & 3;
    const int tx = tid & 15;
    const int ty = tid >> 4;
    const int r0 = bx * 64;
    const int c0 = by * 128;
    const bool isq = (c0 < 256);

    const float* W = isq ? (Wq + (size_t)c0 * 1024)
                         : (Wk + (size_t)(c0 - 256) * 1024);
    const float* bias = isq ? (bq + c0) : (bk + (c0 - 256));

    const bool isA = (tid < 128);
    const int sArow = tid >> 1, sAk = (tid & 1) * 4;
    const int sWrow = tid >> 1, sWk = (tid & 1) * 4;

    float acc[4][8] = {};
    float4 rA, rW;

    if (isA) rA = *(const float4*)&mu[(size_t)(r0 + sArow) * 1024 + sAk];
    rW = *(const float4*)&W[(size_t)sWrow * 1024 + sWk];
    if (isA) {
        As[0][sAk + 0][sArow] = rA.x; As[0][sAk + 1][sArow] = rA.y;
        As[0][sAk + 2][sArow] = rA.z; As[0][sAk + 3][sArow] = rA.w;
    }
    Ws[0][sWk + 0][sWrow] = rW.x; Ws[0][sWk + 1][sWrow] = rW.y;
    Ws[0][sWk + 2][sWrow] = rW.z; Ws[0][sWk + 3][sWrow] = rW.w;
    __syncthreads();

    int buf = 0;
    for (int k0 = 0; k0 < 1024; k0 += 8) {
        const bool has = (k0 + 8 < 1024);
        if (has) {
            if (isA) rA = *(const float4*)&mu[(size_t)(r0 + sArow) * 1024 + k0 + 8 + sAk];
            rW = *(const float4*)&W[(size_t)sWrow * 1024 + k0 + 8 + sWk];
        }
        #pragma unroll
        for (int kk = 0; kk < 8; ++kk) {
            float4 a  = *(const float4*)&As[buf][kk][ty * 4];
            float4 b0 = *(const float4*)&Ws[buf][kk][tx * 8];
            float4 b1 = *(const float4*)&Ws[buf][kk][tx * 8 + 4];
            float av[4] = {a.x, a.y, a.z, a.w};
            float bv[8] = {b0.x, b0.y, b0.z, b0.w, b1.x, b1.y, b1.z, b1.w};
            #pragma unroll
            for (int i = 0; i < 4; ++i)
                #pragma unroll
                for (int j = 0; j < 8; ++j)
                    acc[i][j] += av[i] * bv[j];
        }
        if (has) {
            int nb = buf ^ 1;
            if (isA) {
                As[nb][sAk + 0][sArow] = rA.x; As[nb][sAk + 1][sArow] = rA.y;
                As[nb][sAk + 2][sArow] = rA.z; As[nb][sAk + 3][sArow] = rA.w;
            }
            Ws[nb][sWk + 0][sWrow] = rW.x; Ws[nb][sWk + 1][sWrow] = rW.y;
            Ws[nb][sWk + 2][sWrow] = rW.z; Ws[nb][sWk + 3][sWrow] = rW.w;
        }
        __syncthreads();
        buf ^= 1;
    }

    const int lcol = (c0 & 255) + tx * 8;
    #pragma unroll
    for (int i = 0; i < 4; ++i) {
        int row = r0 + ty * 4 + i;
        float o[8];
        #pragma unroll
        for (int j = 0; j < 8; ++j) o[j] = acc[i][j] + bias[tx * 8 + j];
        float* dst = isq ? &q_[(size_t)row * MMDIM + lcol]
                         : &k_[(size_t)row * MMDIM + lcol];
        *(float4*)dst       = make_float4(o[0], o[1], o[2], o[3]);
        *(float4*)(dst + 4) = make_float4(o[4], o[5], o[6], o[7]);
        size_t srow = isq ? (size_t)row : (size_t)(RTOT + row);
        short8_t sh, sl;
        #pragma unroll
        for (int j = 0; j < 8; ++j) {
            unsigned short h = f2bf(o[j]);
            sh[j] = (short)h;
            sl[j] = (short)f2bf(o[j] - __uint_as_float((unsigned)h << 16));
        }
        *(short8_t*)&qkh[srow * MMDIM + lcol] = sh;
        *(short8_t*)&qkl[srow * MMDIM + lcol] = sl;
    }
}

// ---------------------------------------------------------------------------
// Split-bf16 3-pass MFMA GEMM body (linear-path tensors: v, h, sq, out).
// ---------------------------------------------------------------------------
template<int ASRC, int WITH_GATE>
__device__ __forceinline__ void gemm_mfma_body(
    unsigned short (*Ah)[72], unsigned short (*Al)[72],
    unsigned short (*Bh)[72], unsigned short (*Bl)[72],
    const float* __restrict__ A, const float* __restrict__ lam,
    const float* __restrict__ pi,
    const unsigned short* __restrict__ Wh, const unsigned short* __restrict__ Wl,
    const float* __restrict__ bias, const float* __restrict__ gate,
    float* __restrict__ C, int K, int N, int bx, int by)
{
    const int tid = threadIdx.x;
    const int lane = tid & 63;
    const int wv = tid >> 6;
    const int r0 = bx * 64;
    const int c0 = by * 128;

    f32x4 acc0[8] = {}, acc1[8] = {}, acc2[8] = {};

    const int arow = wv * 16 + (lane & 15);
    const int koff = (lane >> 4) * 8;

    for (int kc = 0; kc < K; kc += 64) {
        #pragma unroll
        for (int i = 0; i < 2; ++i) {
            int g = tid + i * 256;
            int row = g >> 3, gq = g & 7;
            float x[8];
            if (ASRC == 0) {
                float4 v0 = *(const float4*)&A[(size_t)(r0 + row) * K + kc + gq * 8];
                float4 v1 = *(const float4*)&A[(size_t)(r0 + row) * K + kc + gq * 8 + 4];
                x[0] = v0.x; x[1] = v0.y; x[2] = v0.z; x[3] = v0.w;
                x[4] = v1.x; x[5] = v1.y; x[6] = v1.z; x[7] = v1.w;
            } else {
                #pragma unroll
                for (int e = 0; e < 8; ++e) {
                    int c = kc + gq * 8 + e;
                    float val;
                    if (c < 1024)      val = A[(size_t)(r0 + row) * 1024 + c];
                    else if (c < 2048) val = -logf(fmaxf(lam[(size_t)(r0 + row) * 1024 + (c - 1024)], 1e-6f));
                    else if (c < 2055) val = pi[(size_t)(r0 + row) * 7 + (c - 2048)];
                    else               val = 0.f;
                    x[e] = val;
                }
            }
            short8_t sh, sl;
            #pragma unroll
            for (int e = 0; e < 8; ++e) {
                unsigned short h = f2bf(x[e]);
                sh[e] = (short)h;
                sl[e] = (short)f2bf(x[e] - __uint_as_float((unsigned)h << 16));
            }
            *(short8_t*)&Ah[row][gq * 8] = sh;
            *(short8_t*)&Al[row][gq * 8] = sl;
        }
        #pragma unroll
        for (int i = 0; i < 4; ++i) {
            int g = tid + i * 256;
            int row = g >> 3, gq = g & 7;
            *(short8_t*)&Bh[row][gq * 8] = *(const short8_t*)&Wh[(size_t)(c0 + row) * K + kc + gq * 8];
            *(short8_t*)&Bl[row][gq * 8] = *(const short8_t*)&Wl[(size_t)(c0 + row) * K + kc + gq * 8];
        }
        __syncthreads();
        #pragma unroll
        for (int kt = 0; kt < 2; ++kt) {
            short8_t afh = *(const short8_t*)&Ah[arow][kt * 32 + koff];
            short8_t afl = *(const short8_t*)&Al[arow][kt * 32 + koff];
            #pragma unroll
            for (int ct = 0; ct < 8; ++ct) {
                short8_t bh = *(const short8_t*)&Bh[ct * 16 + (lane & 15)][kt * 32 + koff];
                short8_t bl = *(const short8_t*)&Bl[ct * 16 + (lane & 15)][kt * 32 + koff];
                acc0[ct] = __builtin_amdgcn_mfma_f32_16x16x32_bf16(afh, bh, acc0[ct], 0, 0, 0);
                acc1[ct] = __builtin_amdgcn_mfma_f32_16x16x32_bf16(afl, bh, acc1[ct], 0, 0, 0);
                acc2[ct] = __builtin_amdgcn_mfma_f32_16x16x32_bf16(afh, bl, acc2[ct], 0, 0, 0);
            }
        }
        __syncthreads();
    }

    float g = 1.f;
    if (WITH_GATE) g = 1.f / (1.f + expf(-gate[0]));
    #pragma unroll
    for (int ct = 0; ct < 8; ++ct) {
        int col = c0 + ct * 16 + (lane & 15);
        float b = bias[col];
        #pragma unroll
        for (int r = 0; r < 4; ++r) {
            int row = r0 + wv * 16 + (lane >> 4) * 4 + r;
            C[(size_t)row * N + col] = (acc0[ct][r] + acc1[ct][r] + acc2[ct][r] + b) * g;
        }
    }
}

template<int ASRC, int WITH_GATE>
__global__ __launch_bounds__(256) void gemm_mfma(
    const float* __restrict__ A, const float* __restrict__ lam,
    const float* __restrict__ pi,
    const unsigned short* __restrict__ Wh, const unsigned short* __restrict__ Wl,
    const float* __restrict__ bias, const float* __restrict__ gate,
    float* __restrict__ C, int K, int N)
{
    __shared__ unsigned short Ah[64][72], Al[64][72];
    __shared__ unsigned short Bh[128][72], Bl[128][72];
    gemm_mfma_body<ASRC, WITH_GATE>(Ah, Al, Bh, Bl, A, lam, pi, Wh, Wl,
                                    bias, gate, C, K, N, blockIdx.x, blockIdx.y);
}

// fused v + h projections: grid (128, 4); y<2 -> v, y>=2 -> h
__global__ __launch_bounds__(256) void gemm_vh(
    const float* __restrict__ mu, const float* __restrict__ lam,
    const float* __restrict__ pi,
    const unsigned short* __restrict__ wvh, const unsigned short* __restrict__ wvl,
    const float* __restrict__ bv,
    const unsigned short* __restrict__ w1h, const unsigned short* __restrict__ w1l,
    const float* __restrict__ bs1,
    float* __restrict__ v_, float* __restrict__ h_)
{
    __shared__ unsigned short Ah[64][72], Al[64][72];
    __shared__ unsigned short Bh[128][72], Bl[128][72];
    if (blockIdx.y < 2)
        gemm_mfma_body<0, 0>(Ah, Al, Bh, Bl, mu, nullptr, nullptr, wvh, wvl,
                             bv, nullptr, v_, 1024, 256, blockIdx.x, blockIdx.y);
    else
        gemm_mfma_body<1, 0>(Ah, Al, Bh, Bl, mu, lam, pi, w1h, w1l,
                             bs1, nullptr, h_, 2112, 256, blockIdx.x, blockIdx.y - 2);
}

// ---------------------------------------------------------------------------
// Fused tree levels 1..6 from leaves, local w-subtree (bit-identical order).
// ---------------------------------------------------------------------------
__global__ __launch_bounds__(256) void tree_all(
    const float* __restrict__ kleaf, const float* __restrict__ vleaf,
    const float* __restrict__ pw, float* __restrict__ wl6,
    float* __restrict__ kt_, float* __restrict__ vt_,
    unsigned short* __restrict__ kth, unsigned short* __restrict__ ktl)
{
    __shared__ float kb[254][64];
    __shared__ float vb[254][64];
    __shared__ float wl[254];
    const int tid = threadIdx.x;
    const int g  = blockIdx.x >> 2;
    const int mc = blockIdx.x & 3;
    const int b  = blockIdx.y;
    const int wb = b * 4095;

    for (int idx = tid; idx < 128 * 64; idx += 256) {
        int j = idx >> 6, m = idx & 63;
        size_t gi = ((size_t)b * TT + g * 128 + j) * MMDIM + mc * 64 + m;
        kb[j][m] = kleaf[gi];
        vb[j][m] = vleaf[gi];
    }
    if (tid < 128) wl[tid] = pw[b * 4096 + g * 128 + tid];
    __syncthreads();

    int pb = 0, cb = 128;
    for (int l = 1; l <= 6; ++l) {
        int nloc = 128 >> l;
        int offl = TT - (8192 >> l);
        int gbase = g * nloc;
        if (tid < nloc)
            wl[cb + tid] = wl[pb + 2 * tid] + wl[pb + 2 * tid + 1] + 1e-8f;
        __syncthreads();
        for (int idx = tid; idx < nloc * 64; idx += 256) {
            int j = idx >> 6, m = idx & 63;
            float w1 = wl[pb + 2 * j];
            float w2 = wl[pb + 2 * j + 1];
            float tw = wl[cb + j];
            float kvv = (w1 * kb[pb + 2 * j][m] + w2 * kb[pb + 2 * j + 1][m]) / tw;
            float vvv = (w1 * vb[pb + 2 * j][m] + w2 * vb[pb + 2 * j + 1][m]) / tw;
            kb[cb + j][m] = kvv;
            vb[cb + j][m] = vvv;
            size_t go = (size_t)(wb + offl + gbase + j) * MMDIM + mc * 64 + m;
            kt_[go] = kvv;
            vt_[go] = vvv;
            unsigned short hh = f2bf(kvv);
            kth[go] = hh;
            ktl[go] = f2bf(kvv - __uint_as_float((unsigned)hh << 16));
        }
        __syncthreads();
        pb = cb; cb += nloc;
    }
    if (mc == 0 && tid < 2) wl6[b * 64 + g * 2 + tid] = wl[pb + tid];
}

// ---------------------------------------------------------------------------
// Fused tree levels 7..12; local w7..12 from exported level-6 weights.
// ---------------------------------------------------------------------------
__global__ __launch_bounds__(256) void tree_deep(
    float* __restrict__ kt_, float* __restrict__ vt_,
    const float* __restrict__ wl6,
    unsigned short* __restrict__ kth, unsigned short* __restrict__ ktl)
{
    __shared__ float kb[128][68];
    __shared__ float vb[128][68];
    __shared__ float wl[127];
    const int tid = threadIdx.x;
    const int mc = blockIdx.x;
    const int b = blockIdx.y;
    const int wb = b * 4095;

    for (int idx = tid; idx < 64 * 64; idx += 256) {
        int j = idx >> 6, m = idx & 63;
        size_t gi = (size_t)(wb + 3968 + j) * MMDIM + mc * 64 + m;
        kb[j][m] = kt_[gi];
        vb[j][m] = vt_[gi];
    }
    if (tid < 64) wl[tid] = wl6[b * 64 + tid];
    __syncthreads();

    int pb = 0;
    int pbw = 0, cbw = 64;
    for (int l = 7; l <= 12; ++l) {
        int nout = 4096 >> l;
        int cb = 128 - (128 >> (l - 6));
        int offl = TT - (8192 >> l);
        if (tid < nout)
            wl[cbw + tid] = wl[pbw + 2 * tid] + wl[pbw + 2 * tid + 1] + 1e-8f;
        __syncthreads();
        for (int idx = tid; idx < nout * 64; idx += 256) {
            int j = idx >> 6, m = idx & 63;
            float w1 = wl[pbw + 2 * j];
            float w2 = wl[pbw + 2 * j + 1];
            float tw = wl[cbw + j];
            float kvv = (w1 * kb[pb + 2 * j][m] + w2 * kb[pb + 2 * j + 1][m]) / tw;
            float vvv = (w1 * vb[pb + 2 * j][m] + w2 * vb[pb + 2 * j + 1][m]) / tw;
            kb[cb + j][m] = kvv;
            vb[cb + j][m] = vvv;
            size_t go = (size_t)(wb + offl + j) * MMDIM + mc * 64 + m;
            kt_[go] = kvv;
            vt_[go] = vvv;
            unsigned short hh = f2bf(kvv);
            kth[go] = hh;
            ktl[go] = f2bf(kvv - __uint_as_float((unsigned)hh << 16));
        }
        __syncthreads();
        pb = cb;
        pbw = cbw; cbw += nout;
    }
}

// ---------------------------------------------------------------------------
// packed-key top-k helpers. key = (sortable(score) << 32) | ~idx.
// ---------------------------------------------------------------------------
__device__ __forceinline__ unsigned long long pack_key(float v, int col)
{
    unsigned u = __float_as_uint(v);
    u ^= ((unsigned)((int)u >> 31)) | 0x80000000u;
    return ((unsigned long long)u << 32) | (unsigned)(~col);
}

__device__ __forceinline__ void unpack_key(unsigned long long k, float& v, int& col)
{
    unsigned u = (unsigned)(k >> 32);
    u ^= (u & 0x80000000u) ? 0x80000000u : 0xFFFFFFFFu;
    v = __uint_as_float(u);
    col = (int)(~(unsigned)k);
}

__device__ __forceinline__ unsigned long long shfl_xor_u64(unsigned long long v, int off)
{
    int lo = __shfl_xor((int)(unsigned)v, off);
    int hi = __shfl_xor((int)(v >> 32), off);
    return ((unsigned long long)(unsigned)hi << 32) | (unsigned)lo;
}

__device__ __forceinline__ void ins4u(unsigned long long k, unsigned long long t[4])
{
    if (k <= t[3]) return;
    t[3] = k;
    if (t[3] > t[2]) { unsigned long long x = t[2]; t[2] = t[3]; t[3] = x; }
    if (t[2] > t[1]) { unsigned long long x = t[1]; t[1] = t[2]; t[2] = x; }
    if (t[1] > t[0]) { unsigned long long x = t[0]; t[0] = t[1]; t[1] = x; }
}

__device__ __forceinline__ void ins5u(unsigned long long k, unsigned long long t[5])
{
    if (k <= t[4]) return;
    t[4] = k;
    if (t[4] > t[3]) { unsigned long long x = t[3]; t[3] = t[4]; t[4] = x; }
    if (t[3] > t[2]) { unsigned long long x = t[2]; t[2] = t[3]; t[3] = x; }
    if (t[2] > t[1]) { unsigned long long x = t[1]; t[1] = t[2]; t[2] = x; }
    if (t[1] > t[0]) { unsigned long long x = t[0]; t[0] = t[1]; t[1] = x; }
}

__device__ __forceinline__ bool beats(float v, int id, float v2, int id2)
{
    return (v > v2) || (v == v2 && id < id2);
}

__device__ __forceinline__ void ins5(float v, int id, float tv[5], int ti[5])
{
    if (!beats(v, id, tv[4], ti[4])) return;
    tv[4] = v; ti[4] = id;
    #pragma unroll
    for (int s = 4; s > 0; --s) {
        if (beats(tv[s], ti[s], tv[s - 1], ti[s - 1])) {
            float fv = tv[s]; tv[s] = tv[s - 1]; tv[s - 1] = fv;
            int iv = ti[s]; ti[s] = ti[s - 1]; ti[s - 1] = iv;
        }
    }
}

// slice id -> (level, col base). 39 slices of <=256 cols.
__device__ __forceinline__ void slice_map(int sid, int& level, int& c0)
{
    if (sid < 16)      { level = 0; c0 = sid << 8; }
    else if (sid < 24) { level = 1; c0 = (sid - 16) << 8; }
    else if (sid < 28) { level = 2; c0 = (sid - 24) << 8; }
    else if (sid < 30) { level = 3; c0 = (sid - 28) << 8; }
    else               { level = sid - 26; c0 = 0; }
}

// ---------------------------------------------------------------------------
// MFMA topk — R11 winner, unchanged (219 us measured in R13).
// ---------------------------------------------------------------------------
__global__ __launch_bounds__(256) void topk_mfma(
    const unsigned short* __restrict__ qkh, const unsigned short* __restrict__ qkl,
    const unsigned short* __restrict__ kth, const unsigned short* __restrict__ ktl,
    float2* __restrict__ topw)
{
    __shared__ unsigned short kbh[32][264];
    __shared__ unsigned short kbl[32][264];

    const int tid = threadIdx.x;
    const int lane = tid & 63;
    const int wv = tid >> 6;
    const int r0 = blockIdx.x * 64;
    const int sid = blockIdx.y;
    const int b = r0 >> 12;
    const int t0 = r0 & 4095;

    int level, c0b;
    slice_map(sid, level, c0b);
    const int n = TT >> level;
    const int nv = min(min(n, t0 + 64), c0b + 256);

    if (c0b >= nv) {
        if (tid < 64) {
            float2 e = make_float2(-INFINITY, __int_as_float(0x7fffffff));
            #pragma unroll
            for (int s = 0; s < 5; ++s)
                topw[(size_t)(sid * 5 + s) * RTOT + r0 + tid] = e;
        }
        return;
    }

    const unsigned short* Kh;
    const unsigned short* Kl;
    if (level == 0) {
        Kh = qkh + (size_t)RTOT * MMDIM + (size_t)b * TT * MMDIM;
        Kl = qkl + (size_t)RTOT * MMDIM + (size_t)b * TT * MMDIM;
    } else {
        size_t off = (size_t)b * 4095 + (TT - (8192 >> level));
        Kh = kth + off * MMDIM;
        Kl = ktl + off * MMDIM;
    }

    const int arow = r0 + wv * 16 + (lane & 15);
    const int koff = (lane >> 4) * 8;
    short8_t ah[8], al[8];
    #pragma unroll
    for (int kt = 0; kt < 8; ++kt) {
        ah[kt] = *(const short8_t*)(qkh + (size_t)arow * MMDIM + kt * 32 + koff);
        al[kt] = *(const short8_t*)(qkl + (size_t)arow * MMDIM + kt * 32 + koff);
    }

    unsigned long long tk[4][4] = {};
    const int trow0 = t0 + wv * 16 + (lane >> 4) * 4;

    const int scol = tid >> 3;
    const int kseg = (tid & 7) * 32;

    for (int c0 = c0b; c0 < nv; c0 += 32) {
        {
            int cc = min(c0 + scol, n - 1);
            const unsigned short* gh = Kh + (size_t)cc * MMDIM + kseg;
            const unsigned short* gl = Kl + (size_t)cc * MMDIM + kseg;
            #pragma unroll
            for (int i = 0; i < 4; ++i) {
                *(short8_t*)&kbh[scol][kseg + i * 8] = *(const short8_t*)(gh + i * 8);
                *(short8_t*)&kbl[scol][kseg + i * 8] = *(const short8_t*)(gl + i * 8);
            }
        }
        __syncthreads();

        #pragma unroll
        for (int ct = 0; ct < 2; ++ct) {
            f32x4 a0 = {0.f, 0.f, 0.f, 0.f};
            f32x4 a1 = {0.f, 0.f, 0.f, 0.f};
            f32x4 a2 = {0.f, 0.f, 0.f, 0.f};
            const int bc = ct * 16 + (lane & 15);
            #pragma unroll
            for (int kt = 0; kt < 8; ++kt) {
                short8_t bh = *(const short8_t*)&kbh[bc][kt * 32 + koff];
                short8_t bl = *(const short8_t*)&kbl[bc][kt * 32 + koff];
                a0 = __builtin_amdgcn_mfma_f32_16x16x32_bf16(ah[kt], bh, a0, 0, 0, 0);
                a1 = __builtin_amdgcn_mfma_f32_16x16x32_bf16(al[kt], bh, a1, 0, 0, 0);
                a2 = __builtin_amdgcn_mfma_f32_16x16x32_bf16(ah[kt], bl, a2, 0, 0, 0);
            }
            const int col = c0 + bc;
            #pragma unroll
            for (int r = 0; r < 4; ++r) {
                float sc = (a0[r] + a1[r] + a2[r]) * 0.0625f;
                unsigned long long key =
                    (col <= trow0 + r && col < n) ? pack_key(sc, col) : 0ull;
                if (__any(key > tk[r][3])) ins4u(key, tk[r]);
            }
        }
        __syncthreads();
    }

    #pragma unroll
    for (int r = 0; r < 4; ++r) {
        unsigned long long k5[5];
        #pragma unroll
        for (int s = 0; s < 4; ++s) k5[s] = tk[r][s];
        k5[4] = 0ull;
        #pragma unroll
        for (int pass = 0; pass < 4; ++pass) {
            int off = 1 << pass;
            unsigned long long o[5];
            #pragma unroll
            for (int s = 0; s < 5; ++s) o[s] = shfl_xor_u64(k5[s], off);
            #pragma unroll
            for (int s = 0; s < 5; ++s) ins5u(o[s], k5);
        }
        if ((lane & 15) == 0) {
            int row = r0 + wv * 16 + (lane >> 4) * 4 + r;
            #pragma unroll
            for (int s = 0; s < 5; ++s) {
                float2 e;
                if (k5[s] == 0ull) {
                    e = make_float2(-INFINITY, __int_as_float(0x7fffffff));
                } else {
                    float v; int c;
                    unpack_key(k5[s], v, c);
                    e = make_float2(v, __int_as_float(c));
                }
                topw[(size_t)(sid * 5 + s) * RTOT + row] = e;
            }
        }
    }
}

// ---------------------------------------------------------------------------
// Phase 2 (fused with s_scratch): per row, compute s gate + kappa + scratch
// attention in-register (same ops/order as the old s_scratch_kernel; the f32
// memory round-trip it replaces is exact), then merge slice top-5s per level,
// ambiguous rescore, softmax, kappa-weighted V gather; write ctx once.
// One wave per row.
// ---------------------------------------------------------------------------
__global__ __launch_bounds__(256) void merge_gather(
    const float2* __restrict__ topw, const float* __restrict__ q,
    const float* __restrict__ kl0, const float* __restrict__ ktf,
    const float* __restrict__ vl0, const float* __restrict__ vtree,
    const float* __restrict__ h_, const float* __restrict__ Ws2,
    const float* __restrict__ bs2, const float* __restrict__ sq_,
    const float* __restrict__ scr, float* __restrict__ ctx)
{
    const int tid = threadIdx.x;
    const int lane = tid & 63;
    const int wv = __builtin_amdgcn_readfirstlane(tid >> 6);
    const int row = blockIdx.x * 4 + wv;
    const int b = row >> 12;

    // --- s gate (identical to s_scratch_kernel) ---
    float4 hv = *(const float4*)&h_[(size_t)row * MMDIM + lane * 4];
    float4 wv2 = *(const float4*)&Ws2[lane * 4];
    float p = 0.f;
    p += (hv.x / (1.f + expf(-hv.x))) * wv2.x;
    p += (hv.y / (1.f + expf(-hv.y))) * wv2.y;
    p += (hv.z / (1.f + expf(-hv.z))) * wv2.z;
    p += (hv.w / (1.f + expf(-hv.w))) * wv2.w;
    #pragma unroll
    for (int o = 32; o; o >>= 1) p += __shfl_xor(p, o);

    float z = p + bs2[0];
    float s = 1.f / (1.f + expf(-z));
    float c = s * 12.f;
    float Z = 0.f;
    #pragma unroll
    for (int l = 0; l < 13; ++l) {
        float d = (float)l - c;
        Z += expf(-0.5f * d * d);
    }
    Z = fmaxf(Z, 1e-8f);

    // --- scratch attention, blend = s (identical ops/order) ---
    float4 o4;
    {
        float4 qv = *(const float4*)&sq_[(size_t)row * MMDIM + lane * 4];
        float4 fr[8];
        float sc[8];
        #pragma unroll
        for (int ss = 0; ss < 8; ++ss) {
            fr[ss] = *(const float4*)&scr[ss * MMDIM + lane * 4];
            sc[ss] = qv.x * fr[ss].x + qv.y * fr[ss].y + qv.z * fr[ss].z + qv.w * fr[ss].w;
        }
        #pragma unroll
        for (int ss = 0; ss < 8; ++ss) {
            #pragma unroll
            for (int o = 32; o; o >>= 1) sc[ss] += __shfl_xor(sc[ss], o);
            sc[ss] *= 0.0625f;
        }
        float mx = sc[0];
        #pragma unroll
        for (int ss = 1; ss < 8; ++ss) mx = fmaxf(mx, sc[ss]);
        float sum = 0.f;
        #pragma unroll
        for (int ss = 0; ss < 8; ++ss) { sc[ss] = expf(sc[ss] - mx); sum += sc[ss]; }
        float inv = 1.f / sum;
        o4 = make_float4(0.f, 0.f, 0.f, 0.f);
        #pragma unroll
        for (int ss = 0; ss < 8; ++ss) {
            float pp = sc[ss] * inv;
            o4.x += pp * fr[ss].x; o4.y += pp * fr[ss].y;
            o4.z += pp * fr[ss].z; o4.w += pp * fr[ss].w;
        }
        o4.x *= s; o4.y *= s; o4.z *= s; o4.w *= s;
    }

    float cr[4] = {0, 0, 0, 0};
    const float4 q4 = *(const float4*)&q[(size_t)row * MMDIM + lane * 4];

    for (int l = 0; l <= 12; ++l) {
        int s0, cnt;
        if (l == 0)      { s0 = 0;  cnt = 16; }
        else if (l == 1) { s0 = 16; cnt = 8; }
        else if (l == 2) { s0 = 24; cnt = 4; }
        else if (l == 3) { s0 = 28; cnt = 2; }
        else             { s0 = 26 + l; cnt = 1; }

        float tv[5]; int ti[5];
        #pragma unroll
        for (int ss = 0; ss < 5; ++ss) { tv[ss] = -INFINITY; ti[ss] = 0x7fffffff; }
        for (int sl = 0; sl < cnt; ++sl) {
            #pragma unroll
            for (int ss = 0; ss < 5; ++ss) {
                float2 e = topw[(size_t)((s0 + sl) * 5 + ss) * RTOT + row];
                if (e.x > -INFINITY) ins5(e.x, __float_as_int(e.y), tv, ti);
            }
        }

        const float* Kf = (l == 0)
            ? kl0 + (size_t)b * TT * MMDIM
            : ktf + ((size_t)b * 4095 + (TT - (8192 >> l))) * MMDIM;

        bool ambig = (l <= 9) && (tv[3] - tv[4] < 1e-4f);
        if (ambig) {
            float rv[5]; int ri[5];
            #pragma unroll
            for (int ss = 0; ss < 5; ++ss) { rv[ss] = -INFINITY; ri[ss] = 0x7fffffff; }
            for (int sl = 0; sl < cnt; ++sl) {
                #pragma unroll
                for (int ss = 0; ss < 5; ++ss) {
                    float2 e = topw[(size_t)((s0 + sl) * 5 + ss) * RTOT + row];
                    if (e.x > -INFINITY) {
                        int idx = __float_as_int(e.y);
                        float4 k4 = *(const float4*)&Kf[(size_t)idx * MMDIM + lane * 4];
                        float pp = q4.x * k4.x + q4.y * k4.y + q4.z * k4.z + q4.w * k4.w;
                        #pragma unroll
                        for (int o = 32; o; o >>= 1) pp += __shfl_xor(pp, o);
                        ins5(pp * 0.0625f, idx, rv, ri);
                    }
                }
            }
            #pragma unroll
            for (int ss = 0; ss < 5; ++ss) { tv[ss] = rv[ss]; ti[ss] = ri[ss]; }
        }

        float m0 = tv[0];
        float e0 = expf(tv[0] - m0);
        float e1 = expf(tv[1] - m0);
        float e2 = expf(tv[2] - m0);
        float e3 = expf(tv[3] - m0);
        float sum = e0 + e1 + e2 + e3;
        float d = (float)l - c;
        float kp = (1.f - s) * expf(-0.5f * d * d) / Z;
        float scl = kp / sum;
        float ps[4] = {e0 * scl, e1 * scl, e2 * scl, e3 * scl};

        const float* Vb = (l == 0)
            ? vl0 + (size_t)b * TT * MMDIM
            : vtree + ((size_t)b * 4095 + (TT - (8192 >> l))) * MMDIM;

        #pragma unroll
        for (int ss = 0; ss < 4; ++ss) {
            if (ps[ss] > 0.f) {
                float4 vv = *(const float4*)&Vb[(size_t)ti[ss] * MMDIM + lane * 4];
                cr[0] += ps[ss] * vv.x; cr[1] += ps[ss] * vv.y;
                cr[2] += ps[ss] * vv.z; cr[3] += ps[ss] * vv.w;
            }
        }
    }

    float* cp = ctx + (size_t)row * MMDIM + lane * 4;
    float4 cc = o4;
    cc.x += cr[0]; cc.y += cr[1]; cc.z += cr[2]; cc.w += cr[3];
    *(float4*)cp = cc;
}

// ---------------------------------------------------------------------------
extern "C" void kernel_launch(void* const* d_in, const int* in_sizes, int n_in,
                              void* d_out, int out_size, void* d_ws, size_t ws_size,
                              hipStream_t stream)
{
    const float* mu  = (const float*)d_in[0];
    const float* lam = (const float*)d_in[1];
    const float* pi  = (const float*)d_in[2];
    const float* pw  = (const float*)d_in[3];
    const float* Wq  = (const float*)d_in[4];
    const float* bq  = (const float*)d_in[5];
    const float* Wk  = (const float*)d_in[6];
    const float* bk  = (const float*)d_in[7];
    const float* Wv  = (const float*)d_in[8];
    const float* bv  = (const float*)d_in[9];
    const float* Wo  = (const float*)d_in[10];
    const float* bo  = (const float*)d_in[11];
    const float* Ws1 = (const float*)d_in[12];
    const float* bs1 = (const float*)d_in[13];
    const float* Ws2 = (const float*)d_in[14];
    const float* bs2 = (const float*)d_in[15];
    const float* Wsr = (const float*)d_in[16];
    const float* bsr = (const float*)d_in[17];
    const float* scr = (const float*)d_in[18];
    const float* gate = (const float*)d_in[19];
    float* out = (float*)d_out;

    float* w = (float*)d_ws;
    const size_t RM = (size_t)RTOT * MMDIM;
    float* q_   = w;  w += RM;
    float* k_   = w;  w += RM;
    float* v_   = w;  w += RM;
    float* h_   = w;  w += RM;
    float* sq_  = w;  w += RM;
    float* ctx_ = w;  w += RM;
    float* sb_  = w;  w += RTOT;                    // unused (kept for layout)
    float* kap_ = w;  w += (size_t)RTOT * 16;       // unused (kept for layout)
    float* kt_  = w;  w += (size_t)BB * 4095 * MMDIM;
    float* vt_  = w;  w += (size_t)BB * 4095 * MMDIM;
    float* wl6_ = w;  w += (size_t)BB * 4095;       // only first BB*64 used
    unsigned short* qkh_ = (unsigned short*)w;  w += RM;      // 2*RM ushorts
    unsigned short* qkl_ = (unsigned short*)w;  w += RM;
    unsigned short* kth_ = (unsigned short*)w;  w += (size_t)BB * 4095 * MMDIM / 2;
    unsigned short* ktl_ = (unsigned short*)w;  w += (size_t)BB * 4095 * MMDIM / 2;
    float2* topw = (float2*)w;  w += (size_t)NSLICE * 5 * RTOT * 2;
    unsigned short* w1h_ = (unsigned short*)w;  w += (size_t)256 * 2112 / 2;
    unsigned short* w1l_ = (unsigned short*)w;  w += (size_t)256 * 2112 / 2;
    unsigned short* wvh_ = (unsigned short*)w;  w += (size_t)256 * 1024 / 2;
    unsigned short* wvl_ = (unsigned short*)w;  w += (size_t)256 * 1024 / 2;
    unsigned short* wsrh_ = (unsigned short*)w; w += (size_t)256 * 256 / 2;
    unsigned short* wsrl_ = (unsigned short*)w; w += (size_t)256 * 256 / 2;
    unsigned short* woh_ = (unsigned short*)w;  w += (size_t)1024 * 256 / 2;
    unsigned short* wol_ = (unsigned short*)w;  w += (size_t)1024 * 256 / 2;
    (void)sb_; (void)kap_;

    // L1: q,k exact f32 GEMM + all weight splits
    gemm_qk_split<<<1344, 256, 0, stream>>>(mu, Wq, bq, Wk, bk, q_, k_,
                                            qkh_, qkl_, Ws1, Wv, Wsr, Wo,
                                            w1h_, w1l_, wvh_, wvl_,
                                            wsrh_, wsrl_, woh_, wol_);

    // L2: v + h projections fused (split MFMA)
    gemm_vh<<<dim3(128, 4), 256, 0, stream>>>(mu, lam, pi, wvh_, wvl_, bv,
                                              w1h_, w1l_, bs1, v_, h_);
    // L3: sq projection
    gemm_mfma<0, 0><<<dim3(128, 2), 256, 0, stream>>>(q_, nullptr, nullptr, wsrh_, wsrl_,
                                                      bsr, nullptr, sq_, 256, 256);

    // L4/L5: weighted binary tree (local w-subtrees)
    tree_all<<<dim3(128, BB), 256, 0, stream>>>(k_, v_, pw, wl6_, kt_, vt_,
                                                kth_, ktl_);
    tree_deep<<<dim3(4, BB), 256, 0, stream>>>(kt_, vt_, wl6_, kth_, ktl_);

    // L6: topk (all 39 slices)
    topk_mfma<<<dim3(128, NSLICE), 256, 0, stream>>>(qkh_, qkl_, kth_, ktl_, topw);

    // L7: merge + s/kappa/scratch fused
    merge_gather<<<2048, 256, 0, stream>>>(topw, q_, k_, kt_, v_, vt_,
                                           h_, Ws2, bs2, sq_, scr, ctx_);

    // L8: output projection
    gemm_mfma<0, 1><<<dim3(128, 8), 256, 0, stream>>>(ctx_, nullptr, nullptr, woh_, wol_,
                                                      bo, gate, out, 256, 1024);
}

// Round 16
// 720.118 us; speedup vs baseline: 1.0893x; 1.0893x over previous
//
#include <hip/hip_runtime.h>
#include <math.h>

#define TT 4096
#define BB 2
#define MMDIM 256
#define RTOT 8192
#define NSLICE 39

typedef __attribute__((ext_vector_type(8))) short short8_t;
typedef __attribute__((ext_vector_type(4))) float f32x4;

// ---------------------------------------------------------------------------
// f32 -> bf16 hi/lo split helpers (RNE both stages).
// ---------------------------------------------------------------------------
__device__ __forceinline__ unsigned short f2bf(float x)
{
    unsigned u = __float_as_uint(x);
    u += 0x7fffu + ((u >> 16) & 1u);
    return (unsigned short)(u >> 16);
}

__device__ __forceinline__ void split4(const float* src, unsigned short* hi,
                                       unsigned short* lo, int i)
{
    float4 x = ((const float4*)src)[i];
    ushort4 h, l;
    h.x = f2bf(x.x); l.x = f2bf(x.x - __uint_as_float((unsigned)h.x << 16));
    h.y = f2bf(x.y); l.y = f2bf(x.y - __uint_as_float((unsigned)h.y << 16));
    h.z = f2bf(x.z); l.z = f2bf(x.z - __uint_as_float((unsigned)h.z << 16));
    h.w = f2bf(x.w); l.w = f2bf(x.w - __uint_as_float((unsigned)h.w << 16));
    ((ushort4*)hi)[i] = h;
    ((ushort4*)lo)[i] = l;
}

// ---------------------------------------------------------------------------
// L1: fused q+k f32 GEMM (R11 proven shape, bit-identical q,k) + all weight
// splits. Block ranges: [0,512) qk; [512,768) Ws1; [768,1024) Wv;
// [1024,1088) Wsr; [1088,1344) Wo.
// ---------------------------------------------------------------------------
__global__ __launch_bounds__(256) void gemm_qk_split(
    const float* __restrict__ mu, const float* __restrict__ Wq,
    const float* __restrict__ bq, const float* __restrict__ Wk,
    const float* __restrict__ bk, float* __restrict__ q_, float* __restrict__ k_,
    unsigned short* __restrict__ qkh, unsigned short* __restrict__ qkl,
    const float* __restrict__ Ws1, const float* __restrict__ Wv,
    const float* __restrict__ Wsr, const float* __restrict__ Wo,
    unsigned short* __restrict__ w1h, unsigned short* __restrict__ w1l,
    unsigned short* __restrict__ wvh, unsigned short* __restrict__ wvl,
    unsigned short* __restrict__ wsrh, unsigned short* __restrict__ wsrl,
    unsigned short* __restrict__ woh, unsigned short* __restrict__ wol)
{
    __shared__ float As[2][8][68];
    __shared__ float Ws[2][8][132];
    const int bid = blockIdx.x;
    const int tid = threadIdx.x;

    if (bid >= 512) {
        const int sid = bid - 512;
        if (sid < 256) {
            int r = sid;
            for (int c = tid; c < 2112; c += 256) {
                float v = (c < 2055) ? Ws1[(size_t)r * 2055 + c] : 0.f;
                unsigned short h = f2bf(v);
                w1h[(size_t)r * 2112 + c] = h;
                w1l[(size_t)r * 2112 + c] = f2bf(v - __uint_as_float((unsigned)h << 16));
            }
        } else if (sid < 512) {
            split4(Wv, wvh, wvl, (sid - 256) * 256 + tid);
        } else if (sid < 576) {
            split4(Wsr, wsrh, wsrl, (sid - 512) * 256 + tid);
        } else {
            split4(Wo, woh, wol, (sid - 576) * 256 + tid);
        }
        return;
    }

    const int bx = bid >> 2;
    const int by = bid & 3;
    const int tx = tid & 15;
    const int ty = tid >> 4;
    const int r0 = bx * 64;
    const int c0 = by * 128;
    const bool isq = (c0 < 256);

    const float* W = isq ? (Wq + (size_t)c0 * 1024)
                         : (Wk + (size_t)(c0 - 256) * 1024);
    const float* bias = isq ? (bq + c0) : (bk + (c0 - 256));

    const bool isA = (tid < 128);
    const int sArow = tid >> 1, sAk = (tid & 1) * 4;
    const int sWrow = tid >> 1, sWk = (tid & 1) * 4;

    float acc[4][8] = {};
    float4 rA, rW;

    if (isA) rA = *(const float4*)&mu[(size_t)(r0 + sArow) * 1024 + sAk];
    rW = *(const float4*)&W[(size_t)sWrow * 1024 + sWk];
    if (isA) {
        As[0][sAk + 0][sArow] = rA.x; As[0][sAk + 1][sArow] = rA.y;
        As[0][sAk + 2][sArow] = rA.z; As[0][sAk + 3][sArow] = rA.w;
    }
    Ws[0][sWk + 0][sWrow] = rW.x; Ws[0][sWk + 1][sWrow] = rW.y;
    Ws[0][sWk + 2][sWrow] = rW.z; Ws[0][sWk + 3][sWrow] = rW.w;
    __syncthreads();

    int buf = 0;
    for (int k0 = 0; k0 < 1024; k0 += 8) {
        const bool has = (k0 + 8 < 1024);
        if (has) {
            if (isA) rA = *(const float4*)&mu[(size_t)(r0 + sArow) * 1024 + k0 + 8 + sAk];
            rW = *(const float4*)&W[(size_t)sWrow * 1024 + k0 + 8 + sWk];
        }
        #pragma unroll
        for (int kk = 0; kk < 8; ++kk) {
            float4 a  = *(const float4*)&As[buf][kk][ty * 4];
            float4 b0 = *(const float4*)&Ws[buf][kk][tx * 8];
            float4 b1 = *(const float4*)&Ws[buf][kk][tx * 8 + 4];
            float av[4] = {a.x, a.y, a.z, a.w};
            float bv[8] = {b0.x, b0.y, b0.z, b0.w, b1.x, b1.y, b1.z, b1.w};
            #pragma unroll
            for (int i = 0; i < 4; ++i)
                #pragma unroll
                for (int j = 0; j < 8; ++j)
                    acc[i][j] += av[i] * bv[j];
        }
        if (has) {
            int nb = buf ^ 1;
            if (isA) {
                As[nb][sAk + 0][sArow] = rA.x; As[nb][sAk + 1][sArow] = rA.y;
                As[nb][sAk + 2][sArow] = rA.z; As[nb][sAk + 3][sArow] = rA.w;
            }
            Ws[nb][sWk + 0][sWrow] = rW.x; Ws[nb][sWk + 1][sWrow] = rW.y;
            Ws[nb][sWk + 2][sWrow] = rW.z; Ws[nb][sWk + 3][sWrow] = rW.w;
        }
        __syncthreads();
        buf ^= 1;
    }

    const int lcol = (c0 & 255) + tx * 8;
    #pragma unroll
    for (int i = 0; i < 4; ++i) {
        int row = r0 + ty * 4 + i;
        float o[8];
        #pragma unroll
        for (int j = 0; j < 8; ++j) o[j] = acc[i][j] + bias[tx * 8 + j];
        float* dst = isq ? &q_[(size_t)row * MMDIM + lcol]
                         : &k_[(size_t)row * MMDIM + lcol];
        *(float4*)dst       = make_float4(o[0], o[1], o[2], o[3]);
        *(float4*)(dst + 4) = make_float4(o[4], o[5], o[6], o[7]);
        size_t srow = isq ? (size_t)row : (size_t)(RTOT + row);
        short8_t sh, sl;
        #pragma unroll
        for (int j = 0; j < 8; ++j) {
            unsigned short h = f2bf(o[j]);
            sh[j] = (short)h;
            sl[j] = (short)f2bf(o[j] - __uint_as_float((unsigned)h << 16));
        }
        *(short8_t*)&qkh[srow * MMDIM + lcol] = sh;
        *(short8_t*)&qkl[srow * MMDIM + lcol] = sl;
    }
}

// ---------------------------------------------------------------------------
// Split-bf16 3-pass MFMA GEMM body (linear-path tensors: v, h, sq, out).
// ---------------------------------------------------------------------------
template<int ASRC, int WITH_GATE>
__device__ __forceinline__ void gemm_mfma_body(
    unsigned short (*Ah)[72], unsigned short (*Al)[72],
    unsigned short (*Bh)[72], unsigned short (*Bl)[72],
    const float* __restrict__ A, const float* __restrict__ lam,
    const float* __restrict__ pi,
    const unsigned short* __restrict__ Wh, const unsigned short* __restrict__ Wl,
    const float* __restrict__ bias, const float* __restrict__ gate,
    float* __restrict__ C, int K, int N, int bx, int by)
{
    const int tid = threadIdx.x;
    const int lane = tid & 63;
    const int wv = tid >> 6;
    const int r0 = bx * 64;
    const int c0 = by * 128;

    f32x4 acc0[8] = {}, acc1[8] = {}, acc2[8] = {};

    const int arow = wv * 16 + (lane & 15);
    const int koff = (lane >> 4) * 8;

    for (int kc = 0; kc < K; kc += 64) {
        #pragma unroll
        for (int i = 0; i < 2; ++i) {
            int g = tid + i * 256;
            int row = g >> 3, gq = g & 7;
            float x[8];
            if (ASRC == 0) {
                float4 v0 = *(const float4*)&A[(size_t)(r0 + row) * K + kc + gq * 8];
                float4 v1 = *(const float4*)&A[(size_t)(r0 + row) * K + kc + gq * 8 + 4];
                x[0] = v0.x; x[1] = v0.y; x[2] = v0.z; x[3] = v0.w;
                x[4] = v1.x; x[5] = v1.y; x[6] = v1.z; x[7] = v1.w;
            } else {
                #pragma unroll
                for (int e = 0; e < 8; ++e) {
                    int c = kc + gq * 8 + e;
                    float val;
                    if (c < 1024)      val = A[(size_t)(r0 + row) * 1024 + c];
                    else if (c < 2048) val = -logf(fmaxf(lam[(size_t)(r0 + row) * 1024 + (c - 1024)], 1e-6f));
                    else if (c < 2055) val = pi[(size_t)(r0 + row) * 7 + (c - 2048)];
                    else               val = 0.f;
                    x[e] = val;
                }
            }
            short8_t sh, sl;
            #pragma unroll
            for (int e = 0; e < 8; ++e) {
                unsigned short h = f2bf(x[e]);
                sh[e] = (short)h;
                sl[e] = (short)f2bf(x[e] - __uint_as_float((unsigned)h << 16));
            }
            *(short8_t*)&Ah[row][gq * 8] = sh;
            *(short8_t*)&Al[row][gq * 8] = sl;
        }
        #pragma unroll
        for (int i = 0; i < 4; ++i) {
            int g = tid + i * 256;
            int row = g >> 3, gq = g & 7;
            *(short8_t*)&Bh[row][gq * 8] = *(const short8_t*)&Wh[(size_t)(c0 + row) * K + kc + gq * 8];
            *(short8_t*)&Bl[row][gq * 8] = *(const short8_t*)&Wl[(size_t)(c0 + row) * K + kc + gq * 8];
        }
        __syncthreads();
        #pragma unroll
        for (int kt = 0; kt < 2; ++kt) {
            short8_t afh = *(const short8_t*)&Ah[arow][kt * 32 + koff];
            short8_t afl = *(const short8_t*)&Al[arow][kt * 32 + koff];
            #pragma unroll
            for (int ct = 0; ct < 8; ++ct) {
                short8_t bh = *(const short8_t*)&Bh[ct * 16 + (lane & 15)][kt * 32 + koff];
                short8_t bl = *(const short8_t*)&Bl[ct * 16 + (lane & 15)][kt * 32 + koff];
                acc0[ct] = __builtin_amdgcn_mfma_f32_16x16x32_bf16(afh, bh, acc0[ct], 0, 0, 0);
                acc1[ct] = __builtin_amdgcn_mfma_f32_16x16x32_bf16(afl, bh, acc1[ct], 0, 0, 0);
                acc2[ct] = __builtin_amdgcn_mfma_f32_16x16x32_bf16(afh, bl, acc2[ct], 0, 0, 0);
            }
        }
        __syncthreads();
    }

    float g = 1.f;
    if (WITH_GATE) g = 1.f / (1.f + expf(-gate[0]));
    #pragma unroll
    for (int ct = 0; ct < 8; ++ct) {
        int col = c0 + ct * 16 + (lane & 15);
        float b = bias[col];
        #pragma unroll
        for (int r = 0; r < 4; ++r) {
            int row = r0 + wv * 16 + (lane >> 4) * 4 + r;
            C[(size_t)row * N + col] = (acc0[ct][r] + acc1[ct][r] + acc2[ct][r] + b) * g;
        }
    }
}

template<int ASRC, int WITH_GATE>
__global__ __launch_bounds__(256) void gemm_mfma(
    const float* __restrict__ A, const float* __restrict__ lam,
    const float* __restrict__ pi,
    const unsigned short* __restrict__ Wh, const unsigned short* __restrict__ Wl,
    const float* __restrict__ bias, const float* __restrict__ gate,
    float* __restrict__ C, int K, int N)
{
    __shared__ unsigned short Ah[64][72], Al[64][72];
    __shared__ unsigned short Bh[128][72], Bl[128][72];
    gemm_mfma_body<ASRC, WITH_GATE>(Ah, Al, Bh, Bl, A, lam, pi, Wh, Wl,
                                    bias, gate, C, K, N, blockIdx.x, blockIdx.y);
}

// fused v + h projections: grid (128, 4); y<2 -> v, y>=2 -> h
__global__ __launch_bounds__(256) void gemm_vh(
    const float* __restrict__ mu, const float* __restrict__ lam,
    const float* __restrict__ pi,
    const unsigned short* __restrict__ wvh, const unsigned short* __restrict__ wvl,
    const float* __restrict__ bv,
    const unsigned short* __restrict__ w1h, const unsigned short* __restrict__ w1l,
    const float* __restrict__ bs1,
    float* __restrict__ v_, float* __restrict__ h_)
{
    __shared__ unsigned short Ah[64][72], Al[64][72];
    __shared__ unsigned short Bh[128][72], Bl[128][72];
    if (blockIdx.y < 2)
        gemm_mfma_body<0, 0>(Ah, Al, Bh, Bl, mu, nullptr, nullptr, wvh, wvl,
                             bv, nullptr, v_, 1024, 256, blockIdx.x, blockIdx.y);
    else
        gemm_mfma_body<1, 0>(Ah, Al, Bh, Bl, mu, lam, pi, w1h, w1l,
                             bs1, nullptr, h_, 2112, 256, blockIdx.x, blockIdx.y - 2);
}

// ---------------------------------------------------------------------------
// Fused s gate + kappa + scratch attention. One wave per token.
// ---------------------------------------------------------------------------
__global__ __launch_bounds__(256) void s_scratch_kernel(
    const float* __restrict__ h, const float* __restrict__ Ws2,
    const float* __restrict__ bs2, const float* __restrict__ sq,
    const float* __restrict__ scr, float* __restrict__ kap,
    float* __restrict__ ctx)
{
    const int tid = threadIdx.x;
    const int wave = tid >> 6, lane = tid & 63;
    const int t = blockIdx.x * 4 + wave;

    float4 hv = *(const float4*)&h[(size_t)t * MMDIM + lane * 4];
    float4 wv = *(const float4*)&Ws2[lane * 4];
    float p = 0.f;
    p += (hv.x / (1.f + expf(-hv.x))) * wv.x;
    p += (hv.y / (1.f + expf(-hv.y))) * wv.y;
    p += (hv.z / (1.f + expf(-hv.z))) * wv.z;
    p += (hv.w / (1.f + expf(-hv.w))) * wv.w;
    #pragma unroll
    for (int o = 32; o; o >>= 1) p += __shfl_xor(p, o);

    float z = p + bs2[0];
    float s = 1.f / (1.f + expf(-z));
    float c = s * 12.f;
    float Z = 0.f;
    #pragma unroll
    for (int l = 0; l < 13; ++l) {
        float d = (float)l - c;
        Z += expf(-0.5f * d * d);
    }
    Z = fmaxf(Z, 1e-8f);
    if (lane < 13) {
        float d = (float)lane - c;
        kap[(size_t)t * 16 + lane] = (1.f - s) * expf(-0.5f * d * d) / Z;
    }

    float4 qv = *(const float4*)&sq[(size_t)t * MMDIM + lane * 4];
    float4 fr[8];
    float sc[8];
    #pragma unroll
    for (int ss = 0; ss < 8; ++ss) {
        fr[ss] = *(const float4*)&scr[ss * MMDIM + lane * 4];
        sc[ss] = qv.x * fr[ss].x + qv.y * fr[ss].y + qv.z * fr[ss].z + qv.w * fr[ss].w;
    }
    #pragma unroll
    for (int ss = 0; ss < 8; ++ss) {
        #pragma unroll
        for (int o = 32; o; o >>= 1) sc[ss] += __shfl_xor(sc[ss], o);
        sc[ss] *= 0.0625f;
    }
    float mx = sc[0];
    #pragma unroll
    for (int ss = 1; ss < 8; ++ss) mx = fmaxf(mx, sc[ss]);
    float sum = 0.f;
    #pragma unroll
    for (int ss = 0; ss < 8; ++ss) { sc[ss] = expf(sc[ss] - mx); sum += sc[ss]; }
    float inv = 1.f / sum;
    float4 o = {0, 0, 0, 0};
    #pragma unroll
    for (int ss = 0; ss < 8; ++ss) {
        float pp = sc[ss] * inv;
        o.x += pp * fr[ss].x; o.y += pp * fr[ss].y;
        o.z += pp * fr[ss].z; o.w += pp * fr[ss].w;
    }
    o.x *= s; o.y *= s; o.z *= s; o.w *= s;
    *(float4*)&ctx[(size_t)t * MMDIM + lane * 4] = o;
}

// ---------------------------------------------------------------------------
// Fused tree levels 1..6 from leaves, local w-subtree (bit-identical order).
// ---------------------------------------------------------------------------
__global__ __launch_bounds__(256) void tree_all(
    const float* __restrict__ kleaf, const float* __restrict__ vleaf,
    const float* __restrict__ pw, float* __restrict__ wl6,
    float* __restrict__ kt_, float* __restrict__ vt_,
    unsigned short* __restrict__ kth, unsigned short* __restrict__ ktl)
{
    __shared__ float kb[254][64];
    __shared__ float vb[254][64];
    __shared__ float wl[254];
    const int tid = threadIdx.x;
    const int g  = blockIdx.x >> 2;
    const int mc = blockIdx.x & 3;
    const int b  = blockIdx.y;
    const int wb = b * 4095;

    for (int idx = tid; idx < 128 * 64; idx += 256) {
        int j = idx >> 6, m = idx & 63;
        size_t gi = ((size_t)b * TT + g * 128 + j) * MMDIM + mc * 64 + m;
        kb[j][m] = kleaf[gi];
        vb[j][m] = vleaf[gi];
    }
    if (tid < 128) wl[tid] = pw[b * 4096 + g * 128 + tid];
    __syncthreads();

    int pb = 0, cb = 128;
    for (int l = 1; l <= 6; ++l) {
        int nloc = 128 >> l;
        int offl = TT - (8192 >> l);
        int gbase = g * nloc;
        if (tid < nloc)
            wl[cb + tid] = wl[pb + 2 * tid] + wl[pb + 2 * tid + 1] + 1e-8f;
        __syncthreads();
        for (int idx = tid; idx < nloc * 64; idx += 256) {
            int j = idx >> 6, m = idx & 63;
            float w1 = wl[pb + 2 * j];
            float w2 = wl[pb + 2 * j + 1];
            float tw = wl[cb + j];
            float kvv = (w1 * kb[pb + 2 * j][m] + w2 * kb[pb + 2 * j + 1][m]) / tw;
            float vvv = (w1 * vb[pb + 2 * j][m] + w2 * vb[pb + 2 * j + 1][m]) / tw;
            kb[cb + j][m] = kvv;
            vb[cb + j][m] = vvv;
            size_t go = (size_t)(wb + offl + gbase + j) * MMDIM + mc * 64 + m;
            kt_[go] = kvv;
            vt_[go] = vvv;
            unsigned short hh = f2bf(kvv);
            kth[go] = hh;
            ktl[go] = f2bf(kvv - __uint_as_float((unsigned)hh << 16));
        }
        __syncthreads();
        pb = cb; cb += nloc;
    }
    if (mc == 0 && tid < 2) wl6[b * 64 + g * 2 + tid] = wl[pb + tid];
}

// ---------------------------------------------------------------------------
// Fused tree levels 7..12; local w7..12 from exported level-6 weights.
// ---------------------------------------------------------------------------
__global__ __launch_bounds__(256) void tree_deep(
    float* __restrict__ kt_, float* __restrict__ vt_,
    const float* __restrict__ wl6,
    unsigned short* __restrict__ kth, unsigned short* __restrict__ ktl)
{
    __shared__ float kb[128][68];
    __shared__ float vb[128][68];
    __shared__ float wl[127];
    const int tid = threadIdx.x;
    const int mc = blockIdx.x;
    const int b = blockIdx.y;
    const int wb = b * 4095;

    for (int idx = tid; idx < 64 * 64; idx += 256) {
        int j = idx >> 6, m = idx & 63;
        size_t gi = (size_t)(wb + 3968 + j) * MMDIM + mc * 64 + m;
        kb[j][m] = kt_[gi];
        vb[j][m] = vt_[gi];
    }
    if (tid < 64) wl[tid] = wl6[b * 64 + tid];
    __syncthreads();

    int pb = 0;
    int pbw = 0, cbw = 64;
    for (int l = 7; l <= 12; ++l) {
        int nout = 4096 >> l;
        int cb = 128 - (128 >> (l - 6));
        int offl = TT - (8192 >> l);
        if (tid < nout)
            wl[cbw + tid] = wl[pbw + 2 * tid] + wl[pbw + 2 * tid + 1] + 1e-8f;
        __syncthreads();
        for (int idx = tid; idx < nout * 64; idx += 256) {
            int j = idx >> 6, m = idx & 63;
            float w1 = wl[pbw + 2 * j];
            float w2 = wl[pbw + 2 * j + 1];
            float tw = wl[cbw + j];
            float kvv = (w1 * kb[pb + 2 * j][m] + w2 * kb[pb + 2 * j + 1][m]) / tw;
            float vvv = (w1 * vb[pb + 2 * j][m] + w2 * vb[pb + 2 * j + 1][m]) / tw;
            kb[cb + j][m] = kvv;
            vb[cb + j][m] = vvv;
            size_t go = (size_t)(wb + offl + j) * MMDIM + mc * 64 + m;
            kt_[go] = kvv;
            vt_[go] = vvv;
            unsigned short hh = f2bf(kvv);
            kth[go] = hh;
            ktl[go] = f2bf(kvv - __uint_as_float((unsigned)hh << 16));
        }
        __syncthreads();
        pb = cb;
        pbw = cbw; cbw += nout;
    }
}

// ---------------------------------------------------------------------------
// packed-key top-k helpers. key = (sortable(score) << 32) | ~idx.
// ---------------------------------------------------------------------------
__device__ __forceinline__ unsigned long long pack_key(float v, int col)
{
    unsigned u = __float_as_uint(v);
    u ^= ((unsigned)((int)u >> 31)) | 0x80000000u;
    return ((unsigned long long)u << 32) | (unsigned)(~col);
}

__device__ __forceinline__ void unpack_key(unsigned long long k, float& v, int& col)
{
    unsigned u = (unsigned)(k >> 32);
    u ^= (u & 0x80000000u) ? 0x80000000u : 0xFFFFFFFFu;
    v = __uint_as_float(u);
    col = (int)(~(unsigned)k);
}

__device__ __forceinline__ unsigned long long shfl_xor_u64(unsigned long long v, int off)
{
    int lo = __shfl_xor((int)(unsigned)v, off);
    int hi = __shfl_xor((int)(v >> 32), off);
    return ((unsigned long long)(unsigned)hi << 32) | (unsigned)lo;
}

__device__ __forceinline__ void ins4u(unsigned long long k, unsigned long long t[4])
{
    if (k <= t[3]) return;
    t[3] = k;
    if (t[3] > t[2]) { unsigned long long x = t[2]; t[2] = t[3]; t[3] = x; }
    if (t[2] > t[1]) { unsigned long long x = t[1]; t[1] = t[2]; t[2] = x; }
    if (t[1] > t[0]) { unsigned long long x = t[0]; t[0] = t[1]; t[1] = x; }
}

__device__ __forceinline__ void ins5u(unsigned long long k, unsigned long long t[5])
{
    if (k <= t[4]) return;
    t[4] = k;
    if (t[4] > t[3]) { unsigned long long x = t[3]; t[3] = t[4]; t[4] = x; }
    if (t[3] > t[2]) { unsigned long long x = t[2]; t[2] = t[3]; t[3] = x; }
    if (t[2] > t[1]) { unsigned long long x = t[1]; t[1] = t[2]; t[2] = x; }
    if (t[1] > t[0]) { unsigned long long x = t[0]; t[0] = t[1]; t[1] = x; }
}

__device__ __forceinline__ bool beats(float v, int id, float v2, int id2)
{
    return (v > v2) || (v == v2 && id < id2);
}

__device__ __forceinline__ void ins5(float v, int id, float tv[5], int ti[5])
{
    if (!beats(v, id, tv[4], ti[4])) return;
    tv[4] = v; ti[4] = id;
    #pragma unroll
    for (int s = 4; s > 0; --s) {
        if (beats(tv[s], ti[s], tv[s - 1], ti[s - 1])) {
            float fv = tv[s]; tv[s] = tv[s - 1]; tv[s - 1] = fv;
            int iv = ti[s]; ti[s] = ti[s - 1]; ti[s - 1] = iv;
        }
    }
}

// slice id -> (level, col base). 39 slices of <=256 cols.
__device__ __forceinline__ void slice_map(int sid, int& level, int& c0)
{
    if (sid < 16)      { level = 0; c0 = sid << 8; }
    else if (sid < 24) { level = 1; c0 = (sid - 16) << 8; }
    else if (sid < 28) { level = 2; c0 = (sid - 24) << 8; }
    else if (sid < 30) { level = 3; c0 = (sid - 28) << 8; }
    else               { level = sid - 26; c0 = 0; }
}

// ---------------------------------------------------------------------------
// MFMA topk — R11 winner, unchanged (219 us measured in R13).
// ---------------------------------------------------------------------------
__global__ __launch_bounds__(256) void topk_mfma(
    const unsigned short* __restrict__ qkh, const unsigned short* __restrict__ qkl,
    const unsigned short* __restrict__ kth, const unsigned short* __restrict__ ktl,
    float2* __restrict__ topw)
{
    __shared__ unsigned short kbh[32][264];
    __shared__ unsigned short kbl[32][264];

    const int tid = threadIdx.x;
    const int lane = tid & 63;
    const int wv = tid >> 6;
    const int r0 = blockIdx.x * 64;
    const int sid = blockIdx.y;
    const int b = r0 >> 12;
    const int t0 = r0 & 4095;

    int level, c0b;
    slice_map(sid, level, c0b);
    const int n = TT >> level;
    const int nv = min(min(n, t0 + 64), c0b + 256);

    if (c0b >= nv) {
        if (tid < 64) {
            float2 e = make_float2(-INFINITY, __int_as_float(0x7fffffff));
            #pragma unroll
            for (int s = 0; s < 5; ++s)
                topw[(size_t)(sid * 5 + s) * RTOT + r0 + tid] = e;
        }
        return;
    }

    const unsigned short* Kh;
    const unsigned short* Kl;
    if (level == 0) {
        Kh = qkh + (size_t)RTOT * MMDIM + (size_t)b * TT * MMDIM;
        Kl = qkl + (size_t)RTOT * MMDIM + (size_t)b * TT * MMDIM;
    } else {
        size_t off = (size_t)b * 4095 + (TT - (8192 >> level));
        Kh = kth + off * MMDIM;
        Kl = ktl + off * MMDIM;
    }

    const int arow = r0 + wv * 16 + (lane & 15);
    const int koff = (lane >> 4) * 8;
    short8_t ah[8], al[8];
    #pragma unroll
    for (int kt = 0; kt < 8; ++kt) {
        ah[kt] = *(const short8_t*)(qkh + (size_t)arow * MMDIM + kt * 32 + koff);
        al[kt] = *(const short8_t*)(qkl + (size_t)arow * MMDIM + kt * 32 + koff);
    }

    unsigned long long tk[4][4] = {};
    const int trow0 = t0 + wv * 16 + (lane >> 4) * 4;

    const int scol = tid >> 3;
    const int kseg = (tid & 7) * 32;

    for (int c0 = c0b; c0 < nv; c0 += 32) {
        {
            int cc = min(c0 + scol, n - 1);
            const unsigned short* gh = Kh + (size_t)cc * MMDIM + kseg;
            const unsigned short* gl = Kl + (size_t)cc * MMDIM + kseg;
            #pragma unroll
            for (int i = 0; i < 4; ++i) {
                *(short8_t*)&kbh[scol][kseg + i * 8] = *(const short8_t*)(gh + i * 8);
                *(short8_t*)&kbl[scol][kseg + i * 8] = *(const short8_t*)(gl + i * 8);
            }
        }
        __syncthreads();

        #pragma unroll
        for (int ct = 0; ct < 2; ++ct) {
            f32x4 a0 = {0.f, 0.f, 0.f, 0.f};
            f32x4 a1 = {0.f, 0.f, 0.f, 0.f};
            f32x4 a2 = {0.f, 0.f, 0.f, 0.f};
            const int bc = ct * 16 + (lane & 15);
            #pragma unroll
            for (int kt = 0; kt < 8; ++kt) {
                short8_t bh = *(const short8_t*)&kbh[bc][kt * 32 + koff];
                short8_t bl = *(const short8_t*)&kbl[bc][kt * 32 + koff];
                a0 = __builtin_amdgcn_mfma_f32_16x16x32_bf16(ah[kt], bh, a0, 0, 0, 0);
                a1 = __builtin_amdgcn_mfma_f32_16x16x32_bf16(al[kt], bh, a1, 0, 0, 0);
                a2 = __builtin_amdgcn_mfma_f32_16x16x32_bf16(ah[kt], bl, a2, 0, 0, 0);
            }
            const int col = c0 + bc;
            #pragma unroll
            for (int r = 0; r < 4; ++r) {
                float sc = (a0[r] + a1[r] + a2[r]) * 0.0625f;
                unsigned long long key =
                    (col <= trow0 + r && col < n) ? pack_key(sc, col) : 0ull;
                if (__any(key > tk[r][3])) ins4u(key, tk[r]);
            }
        }
        __syncthreads();
    }

    #pragma unroll
    for (int r = 0; r < 4; ++r) {
        unsigned long long k5[5];
        #pragma unroll
        for (int s = 0; s < 4; ++s) k5[s] = tk[r][s];
        k5[4] = 0ull;
        #pragma unroll
        for (int pass = 0; pass < 4; ++pass) {
            int off = 1 << pass;
            unsigned long long o[5];
            #pragma unroll
            for (int s = 0; s < 5; ++s) o[s] = shfl_xor_u64(k5[s], off);
            #pragma unroll
            for (int s = 0; s < 5; ++s) ins5u(o[s], k5);
        }
        if ((lane & 15) == 0) {
            int row = r0 + wv * 16 + (lane >> 4) * 4 + r;
            #pragma unroll
            for (int s = 0; s < 5; ++s) {
                float2 e;
                if (k5[s] == 0ull) {
                    e = make_float2(-INFINITY, __int_as_float(0x7fffffff));
                } else {
                    float v; int c;
                    unpack_key(k5[s], v, c);
                    e = make_float2(v, __int_as_float(c));
                }
                topw[(size_t)(sid * 5 + s) * RTOT + row] = e;
            }
        }
    }
}

// ---------------------------------------------------------------------------
// Phase 2: merge slice top-5s per level; ambiguous rows -> exact f32 rescore;
// softmax, kappa-weighted V gather; add to ctx. One wave per row.
// ---------------------------------------------------------------------------
__global__ __launch_bounds__(256) void merge_gather(
    const float2* __restrict__ topw, const float* __restrict__ q,
    const float* __restrict__ kl0, const float* __restrict__ ktf,
    const float* __restrict__ vl0, const float* __restrict__ vtree,
    const float* __restrict__ kap, float* __restrict__ ctx)
{
    const int tid = threadIdx.x;
    const int lane = tid & 63;
    const int wv = __builtin_amdgcn_readfirstlane(tid >> 6);
    const int row = blockIdx.x * 4 + wv;
    const int b = row >> 12;

    float cr[4] = {0, 0, 0, 0};
    const float4 q4 = *(const float4*)&q[(size_t)row * MMDIM + lane * 4];

    for (int l = 0; l <= 12; ++l) {
        int s0, cnt;
        if (l == 0)      { s0 = 0;  cnt = 16; }
        else if (l == 1) { s0 = 16; cnt = 8; }
        else if (l == 2) { s0 = 24; cnt = 4; }
        else if (l == 3) { s0 = 28; cnt = 2; }
        else             { s0 = 26 + l; cnt = 1; }

        float tv[5]; int ti[5];
        #pragma unroll
        for (int s = 0; s < 5; ++s) { tv[s] = -INFINITY; ti[s] = 0x7fffffff; }
        for (int sl = 0; sl < cnt; ++sl) {
            #pragma unroll
            for (int s = 0; s < 5; ++s) {
                float2 e = topw[(size_t)((s0 + sl) * 5 + s) * RTOT + row];
                if (e.x > -INFINITY) ins5(e.x, __float_as_int(e.y), tv, ti);
            }
        }

        const float* Kf = (l == 0)
            ? kl0 + (size_t)b * TT * MMDIM
            : ktf + ((size_t)b * 4095 + (TT - (8192 >> l))) * MMDIM;

        bool ambig = (l <= 9) && (tv[3] - tv[4] < 1e-4f);
        if (ambig) {
            float rv[5]; int ri[5];
            #pragma unroll
            for (int s = 0; s < 5; ++s) { rv[s] = -INFINITY; ri[s] = 0x7fffffff; }
            for (int sl = 0; sl < cnt; ++sl) {
                #pragma unroll
                for (int s = 0; s < 5; ++s) {
                    float2 e = topw[(size_t)((s0 + sl) * 5 + s) * RTOT + row];
                    if (e.x > -INFINITY) {
                        int idx = __float_as_int(e.y);
                        float4 k4 = *(const float4*)&Kf[(size_t)idx * MMDIM + lane * 4];
                        float p = q4.x * k4.x + q4.y * k4.y + q4.z * k4.z + q4.w * k4.w;
                        #pragma unroll
                        for (int o = 32; o; o >>= 1) p += __shfl_xor(p, o);
                        ins5(p * 0.0625f, idx, rv, ri);
                    }
                }
            }
            #pragma unroll
            for (int s = 0; s < 5; ++s) { tv[s] = rv[s]; ti[s] = ri[s]; }
        }

        float m0 = tv[0];
        float e0 = expf(tv[0] - m0);
        float e1 = expf(tv[1] - m0);
        float e2 = expf(tv[2] - m0);
        float e3 = expf(tv[3] - m0);
        float sum = e0 + e1 + e2 + e3;
        float kp = kap[(size_t)row * 16 + l];
        float scl = kp / sum;
        float ps[4] = {e0 * scl, e1 * scl, e2 * scl, e3 * scl};

        const float* Vb = (l == 0)
            ? vl0 + (size_t)b * TT * MMDIM
            : vtree + ((size_t)b * 4095 + (TT - (8192 >> l))) * MMDIM;

        #pragma unroll
        for (int s = 0; s < 4; ++s) {
            if (ps[s] > 0.f) {
                float4 vv = *(const float4*)&Vb[(size_t)ti[s] * MMDIM + lane * 4];
                cr[0] += ps[s] * vv.x; cr[1] += ps[s] * vv.y;
                cr[2] += ps[s] * vv.z; cr[3] += ps[s] * vv.w;
            }
        }
    }

    float* cp = ctx + (size_t)row * MMDIM + lane * 4;
    float4 c = *(float4*)cp;
    c.x += cr[0]; c.y += cr[1]; c.z += cr[2]; c.w += cr[3];
    *(float4*)cp = c;
}

// ---------------------------------------------------------------------------
extern "C" void kernel_launch(void* const* d_in, const int* in_sizes, int n_in,
                              void* d_out, int out_size, void* d_ws, size_t ws_size,
                              hipStream_t stream)
{
    const float* mu  = (const float*)d_in[0];
    const float* lam = (const float*)d_in[1];
    const float* pi  = (const float*)d_in[2];
    const float* pw  = (const float*)d_in[3];
    const float* Wq  = (const float*)d_in[4];
    const float* bq  = (const float*)d_in[5];
    const float* Wk  = (const float*)d_in[6];
    const float* bk  = (const float*)d_in[7];
    const float* Wv  = (const float*)d_in[8];
    const float* bv  = (const float*)d_in[9];
    const float* Wo  = (const float*)d_in[10];
    const float* bo  = (const float*)d_in[11];
    const float* Ws1 = (const float*)d_in[12];
    const float* bs1 = (const float*)d_in[13];
    const float* Ws2 = (const float*)d_in[14];
    const float* bs2 = (const float*)d_in[15];
    const float* Wsr = (const float*)d_in[16];
    const float* bsr = (const float*)d_in[17];
    const float* scr = (const float*)d_in[18];
    const float* gate = (const float*)d_in[19];
    float* out = (float*)d_out;

    float* w = (float*)d_ws;
    const size_t RM = (size_t)RTOT * MMDIM;
    float* q_   = w;  w += RM;
    float* k_   = w;  w += RM;
    float* v_   = w;  w += RM;
    float* h_   = w;  w += RM;
    float* sq_  = w;  w += RM;
    float* ctx_ = w;  w += RM;
    float* sb_  = w;  w += RTOT;                    // unused (kept for layout)
    float* kap_ = w;  w += (size_t)RTOT * 16;
    float* kt_  = w;  w += (size_t)BB * 4095 * MMDIM;
    float* vt_  = w;  w += (size_t)BB * 4095 * MMDIM;
    float* wl6_ = w;  w += (size_t)BB * 4095;       // only first BB*64 used
    unsigned short* qkh_ = (unsigned short*)w;  w += RM;      // 2*RM ushorts
    unsigned short* qkl_ = (unsigned short*)w;  w += RM;
    unsigned short* kth_ = (unsigned short*)w;  w += (size_t)BB * 4095 * MMDIM / 2;
    unsigned short* ktl_ = (unsigned short*)w;  w += (size_t)BB * 4095 * MMDIM / 2;
    float2* topw = (float2*)w;  w += (size_t)NSLICE * 5 * RTOT * 2;
    unsigned short* w1h_ = (unsigned short*)w;  w += (size_t)256 * 2112 / 2;
    unsigned short* w1l_ = (unsigned short*)w;  w += (size_t)256 * 2112 / 2;
    unsigned short* wvh_ = (unsigned short*)w;  w += (size_t)256 * 1024 / 2;
    unsigned short* wvl_ = (unsigned short*)w;  w += (size_t)256 * 1024 / 2;
    unsigned short* wsrh_ = (unsigned short*)w; w += (size_t)256 * 256 / 2;
    unsigned short* wsrl_ = (unsigned short*)w; w += (size_t)256 * 256 / 2;
    unsigned short* woh_ = (unsigned short*)w;  w += (size_t)1024 * 256 / 2;
    unsigned short* wol_ = (unsigned short*)w;  w += (size_t)1024 * 256 / 2;
    (void)sb_;

    // L1: q,k exact f32 GEMM + all weight splits
    gemm_qk_split<<<1344, 256, 0, stream>>>(mu, Wq, bq, Wk, bk, q_, k_,
                                            qkh_, qkl_, Ws1, Wv, Wsr, Wo,
                                            w1h_, w1l_, wvh_, wvl_,
                                            wsrh_, wsrl_, woh_, wol_);

    // L2: v + h projections fused (split MFMA)
    gemm_vh<<<dim3(128, 4), 256, 0, stream>>>(mu, lam, pi, wvh_, wvl_, bv,
                                              w1h_, w1l_, bs1, v_, h_);
    // L3: sq projection
    gemm_mfma<0, 0><<<dim3(128, 2), 256, 0, stream>>>(q_, nullptr, nullptr, wsrh_, wsrl_,
                                                      bsr, nullptr, sq_, 256, 256);
    // L4: s gate + kappa + scratch attention
    s_scratch_kernel<<<2048, 256, 0, stream>>>(h_, Ws2, bs2, sq_, scr, kap_, ctx_);

    // L5/L6: weighted binary tree (local w-subtrees)
    tree_all<<<dim3(128, BB), 256, 0, stream>>>(k_, v_, pw, wl6_, kt_, vt_,
                                                kth_, ktl_);
    tree_deep<<<dim3(4, BB), 256, 0, stream>>>(kt_, vt_, wl6_, kth_, ktl_);

    // L7: topk (all 39 slices)
    topk_mfma<<<dim3(128, NSLICE), 256, 0, stream>>>(qkh_, qkl_, kth_, ktl_, topw);

    // L8: merge + gather
    merge_gather<<<2048, 256, 0, stream>>>(topw, q_, k_, kt_, v_, vt_, kap_, ctx_);

    // L9: output projection
    gemm_mfma<0, 1><<<dim3(128, 8), 256, 0, stream>>>(ctx_, nullptr, nullptr, woh_, wol_,
                                                      bo, gate, out, 256, 1024);
}